// Round 1
// baseline (922.119 us; speedup 1.0000x reference)
//
#include <hip/hip_runtime.h>
#include <hip/hip_bf16.h>

#define PPB 16
#define NB 8
#define SLOTS 64

// ---------------------------------------------------------------------------
// Layer 1: h1[i,c] = relu( sum_{k,j valid} feats[nbr[i,k],j] * W1[k,j,c] )
// stored as bf16 in workspace. 16 points per 256-thread block; thread = channel.
// ---------------------------------------------------------------------------
__global__ __launch_bounds__(256) void conv1_kernel(
    const float* __restrict__ feats, const float* __restrict__ W1,
    const int* __restrict__ nbr, __hip_bfloat16* __restrict__ h1b, int N) {
  __shared__ float W1s[27 * 256];
  __shared__ float fsT[27][16];   // transposed gathered feats: [k*3+j][p]
  __shared__ int s_nbr[PPB * 9];
  const int c = threadIdx.x;
  const int base = blockIdx.x * PPB;

  for (int t = c; t < 27 * 256; t += 256) W1s[t] = W1[t];
  if (c < PPB * 9) {
    int p = c / 9, k = c - p * 9;
    int gi = base + p;
    s_nbr[c] = (gi < N) ? nbr[gi * 9 + k] : -1;
  }
  __syncthreads();
  if (c < PPB * 9) {
    int p = c / 9, k = c - p * 9;
    int src = s_nbr[c];
    if (src >= 0) {
      fsT[k * 3 + 0][p] = feats[src * 3 + 0];
      fsT[k * 3 + 1][p] = feats[src * 3 + 1];
      fsT[k * 3 + 2][p] = feats[src * 3 + 2];
    } else {
      fsT[k * 3 + 0][p] = 0.f;
      fsT[k * 3 + 1][p] = 0.f;
      fsT[k * 3 + 2][p] = 0.f;
    }
  }
  __syncthreads();

  float acc[PPB];
#pragma unroll
  for (int p = 0; p < PPB; ++p) acc[p] = 0.f;

#pragma unroll 3
  for (int kj = 0; kj < 27; ++kj) {
    float w = W1s[kj * 256 + c];
    const float4* f4 = (const float4*)(&fsT[kj][0]);
    float4 fa = f4[0], fb = f4[1], fc = f4[2], fd = f4[3];
    acc[0]  += fa.x * w; acc[1]  += fa.y * w; acc[2]  += fa.z * w; acc[3]  += fa.w * w;
    acc[4]  += fb.x * w; acc[5]  += fb.y * w; acc[6]  += fb.z * w; acc[7]  += fb.w * w;
    acc[8]  += fc.x * w; acc[9]  += fc.y * w; acc[10] += fc.z * w; acc[11] += fc.w * w;
    acc[12] += fd.x * w; acc[13] += fd.y * w; acc[14] += fd.z * w; acc[15] += fd.w * w;
  }

#pragma unroll
  for (int p = 0; p < PPB; ++p) {
    int gi = base + p;
    if (gi < N) h1b[(long long)gi * 256 + c] = __float2bfloat16(fmaxf(acc[p], 0.f));
  }
}

// ---------------------------------------------------------------------------
// Layer 2 + relu + batched partial mean.
// Center tap (always valid, = self) done as a dense 16-point register-tiled
// matvec-batch; rare off-center taps via a compacted per-block pair list.
// Partial batch sums scattered into SLOTS contention slots.
// ---------------------------------------------------------------------------
__global__ __launch_bounds__(256) void conv2_kernel(
    const __hip_bfloat16* __restrict__ h1b, const float* __restrict__ W2,
    const int* __restrict__ nbr, const int* __restrict__ batch_ids,
    float* __restrict__ psums, float* __restrict__ pcnt, int N) {
  __shared__ float hs[PPB][256];    // gathered h1 rows (fp32)
  __shared__ float outs[PPB][256];  // per-point output tile
  __shared__ int s_nbr[PPB * 9];
  __shared__ int s_batch[PPB];
  __shared__ int lstP[PPB * 8], lstK[PPB * 8], lstS[PPB * 8];
  __shared__ int s_m;
  const int c = threadIdx.x;
  const int base = blockIdx.x * PPB;

  if (c < PPB * 9) {
    int p = c / 9, k = c - p * 9;
    int gi = base + p;
    s_nbr[c] = (gi < N) ? nbr[gi * 9 + k] : -1;
  }
  if (c < PPB) {
    int gi = base + c;
    s_batch[c] = (gi < N) ? batch_ids[gi] : -1;
  }
  __syncthreads();

  if (c == 0) {  // compact off-center valid (p, k, src) pairs
    int m = 0;
    for (int k = 0; k < 9; ++k) {
      if (k == 4) continue;
      for (int p = 0; p < PPB; ++p) {
        int s = s_nbr[p * 9 + k];
        if (s >= 0) { lstP[m] = p; lstK[m] = k; lstS[m] = s; ++m; }
      }
    }
    s_m = m;
  }

  // stage center rows (self) as fp32
#pragma unroll
  for (int p = 0; p < PPB; ++p) {
    int src = s_nbr[p * 9 + 4];
    hs[p][c] = (src >= 0) ? __bfloat162float(h1b[(long long)src * 256 + c]) : 0.f;
  }
  __syncthreads();

  // center tap: dense over 16 points, W2[4] element reused 16x from registers
  float acc[PPB];
#pragma unroll
  for (int p = 0; p < PPB; ++p) acc[p] = 0.f;
  const float* __restrict__ W4 = W2 + 4 * 256 * 256;
  for (int j = 0; j < 256; j += 4) {
    float w0 = W4[(j + 0) * 256 + c];
    float w1 = W4[(j + 1) * 256 + c];
    float w2 = W4[(j + 2) * 256 + c];
    float w3 = W4[(j + 3) * 256 + c];
#pragma unroll
    for (int p = 0; p < PPB; ++p) {
      float4 h4 = *(const float4*)(&hs[p][j]);
      acc[p] += h4.x * w0;
      acc[p] += h4.y * w1;
      acc[p] += h4.z * w2;
      acc[p] += h4.w * w3;
    }
  }
#pragma unroll
  for (int p = 0; p < PPB; ++p) outs[p][c] = acc[p];
  __syncthreads();

  // off-center taps: one matvec per compacted pair (block-uniform)
  const int m = s_m;
  for (int s = 0; s < m; ++s) {
    const int src = lstS[s];
    const int k = lstK[s];
    const int p = lstP[s];
    __syncthreads();  // prior reads of hs[0] done before overwrite
    hs[0][c] = __bfloat162float(h1b[(long long)src * 256 + c]);
    __syncthreads();
    const float* __restrict__ Wk = W2 + k * 256 * 256;
    float pacc = 0.f;
    for (int j = 0; j < 256; j += 4) {
      float4 h4 = *(const float4*)(&hs[0][j]);
      pacc += h4.x * Wk[(j + 0) * 256 + c];
      pacc += h4.y * Wk[(j + 1) * 256 + c];
      pacc += h4.z * Wk[(j + 2) * 256 + c];
      pacc += h4.w * Wk[(j + 3) * 256 + c];
    }
    outs[p][c] += pacc;  // only thread c touches column c — no race
  }

  // epilogue: relu + run-length per-batch partial sums into a contention slot
  const int slot = blockIdx.x & (SLOTS - 1);
  float bsum = 0.f;
  int curb = -2;
#pragma unroll
  for (int p = 0; p < PPB; ++p) {
    int b = s_batch[p];
    if (b < 0) continue;
    float r = fmaxf(outs[p][c], 0.f);
    if (b != curb) {
      if (curb >= 0) atomicAdd(&psums[(slot * NB + curb) * 256 + c], bsum);
      bsum = 0.f;
      curb = b;
    }
    bsum += r;
  }
  if (curb >= 0) atomicAdd(&psums[(slot * NB + curb) * 256 + c], bsum);

  if (c == 0) {
    float cnt = 0.f;
    int cb = -2;
    for (int p = 0; p < PPB; ++p) {
      int b = s_batch[p];
      if (b < 0) continue;
      if (b != cb) {
        if (cb >= 0) atomicAdd(&pcnt[slot * NB + cb], cnt);
        cnt = 0.f;
        cb = b;
      }
      cnt += 1.f;
    }
    if (cb >= 0) atomicAdd(&pcnt[slot * NB + cb], cnt);
  }
}

__global__ __launch_bounds__(256) void finalize_kernel(
    const float* __restrict__ psums, const float* __restrict__ pcnt,
    float* __restrict__ out) {
  const int b = blockIdx.x, c = threadIdx.x;
  float s = 0.f, cnt = 0.f;
  for (int t = 0; t < SLOTS; ++t) s += psums[(t * NB + b) * 256 + c];
  for (int t = 0; t < SLOTS; ++t) cnt += pcnt[t * NB + b];
  out[b * 256 + c] = s / cnt;
}

extern "C" void kernel_launch(void* const* d_in, const int* in_sizes, int n_in,
                              void* d_out, int out_size, void* d_ws, size_t ws_size,
                              hipStream_t stream) {
  const float* feats = (const float*)d_in[0];
  const float* W1    = (const float*)d_in[1];
  const float* W2    = (const float*)d_in[2];
  const int*   nbr   = (const int*)d_in[3];
  const int*   bid   = (const int*)d_in[4];
  float* out = (float*)d_out;
  const int N = in_sizes[0] / 3;

  float* psums = (float*)d_ws;
  float* pcnt  = psums + SLOTS * NB * 256;
  size_t hdr = (size_t)(SLOTS * NB * 256 + SLOTS * NB) * sizeof(float);
  hdr = (hdr + 255) & ~(size_t)255;
  __hip_bfloat16* h1b = (__hip_bfloat16*)((char*)d_ws + hdr);

  hipMemsetAsync(d_ws, 0, hdr, stream);

  const int nblk = (N + PPB - 1) / PPB;
  conv1_kernel<<<nblk, 256, 0, stream>>>(feats, W1, nbr, h1b, N);
  conv2_kernel<<<nblk, 256, 0, stream>>>(h1b, W2, nbr, bid, psums, pcnt, N);
  finalize_kernel<<<NB, 256, 0, stream>>>(psums, pcnt, out);
}